// Round 4
// baseline (350.554 us; speedup 1.0000x reference)
//
#include <hip/hip_runtime.h>

// B=16, C=64->64, H=W=96, 3x3 pad-1 convs + 9-tap dynamic conv from attention.
// All convs: bf16 MFMA implicit GEMM (M=64 co, K=576, N=pixels).
// Scores: bf16 MFMA batched GEMM on class-major layout written by conv epilogue.

typedef __attribute__((ext_vector_type(8))) short short8v;   // 8 bf16 = 4 VGPRs
typedef __attribute__((ext_vector_type(4))) float floatx4;
typedef __attribute__((ext_vector_type(4))) unsigned int uint4v;

constexpr int PLANE = 9216;              // 96*96
constexpr int SCP_STRIDE = 589824;       // 16*9*4096 floats per K-segment

__device__ __forceinline__ unsigned short f2bf(float f) {
    unsigned int u = __float_as_uint(f);
    u = (u + 0x7FFFu + ((u >> 16) & 1u)) >> 16;
    return (unsigned short)u;
}

// ---------- fp32 NCHW -> bf16 NHWC, both inputs in one dispatch -------------
__global__ __launch_bounds__(256) void nchw2nhwc_bf16(
    const float* __restrict__ x1, unsigned short* __restrict__ xh1,
    const float* __restrict__ x2, unsigned short* __restrict__ xh2)
{
    int blk = blockIdx.x;
    const float* x = (blk < 1536) ? x1 : x2;
    unsigned short* xh = (blk < 1536) ? xh1 : xh2;
    if (blk >= 1536) blk -= 1536;
    int b = blk / 96, y = blk - b * 96;
    __shared__ float ls[64][96];
    const float* xp = x + (size_t)b * 64 * PLANE + (size_t)y * 96;
    for (int i = threadIdx.x; i < 64 * 96; i += 256) {
        int ci = i / 96, xc = i - ci * 96;
        ls[ci][xc] = xp[(size_t)ci * PLANE + xc];
    }
    __syncthreads();
    unsigned short* op = xh + ((size_t)b * PLANE + (size_t)y * 96) * 64;
    for (int i = threadIdx.x; i < 96 * 8; i += 256) {
        int xc = i >> 3, cg = i & 7;
        unsigned short tmp[8] __attribute__((aligned(16)));
        #pragma unroll
        for (int j = 0; j < 8; ++j) tmp[j] = f2bf(ls[cg * 8 + j][xc]);
        *(uint4v*)&op[(size_t)xc * 64 + cg * 8] = *(const uint4v*)tmp;
    }
}

// ---------- weights [co][ci][kh][kw] fp32 -> [tap][co][ci] bf16 -------------
__global__ __launch_bounds__(256) void wreorder(
    const float* __restrict__ w1, const float* __restrict__ w2,
    const float* __restrict__ w3, unsigned short* __restrict__ wl)
{
    int blk = blockIdx.x;
    int wi = blk / 9, k9 = blk - wi * 9;
    const float* w = (wi == 0) ? w1 : ((wi == 1) ? w2 : w3);
    unsigned short* o = wl + (size_t)wi * 9 * 4096 + (size_t)k9 * 4096;
    for (int i = threadIdx.x; i < 4096; i += 256)   // i = co*64+ci
        o[i] = f2bf(w[(size_t)i * 9 + k9]);
}

// ---------- MFMA conv v3: 64 co x 128 px (4 rows x 32 cols) per block -------
// 4 waves, wave w = output row w; each wave: all 64 co (4 m-tiles) x 32 px
// (2 n-tiles). Per (tap,ci-half) step: 4 A global (L1-shared) + 2 ds_read_b128
// -> 8 MFMA. Up to 3 convs per dispatch (cid = blk/1152).
// omode: 1 = bf16 NHWC, 2 = fp32 NCHW, 3 = bf16 class-major [b][k9][co][1024]
__global__ __launch_bounds__(256, 4) void conv_mfma(
    const unsigned short* __restrict__ in0,
    const unsigned short* __restrict__ in1,
    const unsigned short* __restrict__ in2,
    const unsigned short* __restrict__ wl,
    void* __restrict__ o0, void* __restrict__ o1, void* __restrict__ o2,
    int om0, int om1, int om2, int dynb)
{
    int blk = blockIdx.x;
    int cid = blk / 1152;
    int r0  = blk - cid * 1152;
    int xs3 = r0 % 3; int t = r0 / 3;
    int yq = t % 24;  int b = t / 24;
    int x0 = xs3 * 32, y0 = yq * 4;

    const unsigned short* xin = (cid == 0) ? in0 : (cid == 1) ? in1 : in2;
    void* out  = (cid == 0) ? o0 : (cid == 1) ? o1 : o2;
    int omode  = (cid == 0) ? om0 : (cid == 1) ? om1 : om2;

    // 6 halo rows x 34 halo cols x 64 ci; 16B-group g of pixel pc at slot g^(pc&7)
    __shared__ __align__(16) unsigned short xs[6 * 34 * 64];

    const unsigned short* xb = xin + (size_t)b * PLANE * 64;
    for (int i = threadIdx.x; i < 1632; i += 256) {
        int g = i & 7, pix = i >> 3;
        int pr = pix / 34, pc = pix - pr * 34;
        int y = y0 - 1 + pr, x = x0 - 1 + pc;
        uint4v v = {0u, 0u, 0u, 0u};
        if ((unsigned)y < 96u && (unsigned)x < 96u)
            v = *(const uint4v*)&xb[((size_t)y * 96 + x) * 64 + g * 8];
        *(uint4v*)&xs[pix * 64 + (g ^ (pc & 7)) * 8] = v;
    }
    __syncthreads();

    int lane = threadIdx.x & 63;
    int w = threadIdx.x >> 6;            // output row within the 4-row tile
    int ln = lane & 15, quad = lane >> 4;

    const unsigned short* wb = wl + (dynb ? (size_t)b * 9 * 4096
                                          : (size_t)cid * 9 * 4096);

    floatx4 acc[4][2];
    #pragma unroll
    for (int m = 0; m < 4; ++m)
        #pragma unroll
        for (int nh = 0; nh < 2; ++nh) acc[m][nh] = (floatx4){0.f, 0.f, 0.f, 0.f};

    #pragma unroll
    for (int k9 = 0; k9 < 9; ++k9) {
        int dy = k9 / 3, dx = k9 - dy * 3;
        #pragma unroll
        for (int ch = 0; ch < 2; ++ch) {
            short8v a[4];
            #pragma unroll
            for (int m = 0; m < 4; ++m)
                a[m] = *(const short8v*)
                    &wb[((size_t)k9 * 64 + m * 16 + ln) * 64 + ch * 32 + quad * 8];
            int gb = ch * 4 + quad;
            short8v bf[2];
            #pragma unroll
            for (int nh = 0; nh < 2; ++nh) {
                int c = nh * 16 + ln + dx;
                int r = w + dy;
                bf[nh] = *(const short8v*)&xs[(r * 34 + c) * 64 + (gb ^ (c & 7)) * 8];
            }
            #pragma unroll
            for (int m = 0; m < 4; ++m)
                #pragma unroll
                for (int nh = 0; nh < 2; ++nh)
                    acc[m][nh] = __builtin_amdgcn_mfma_f32_16x16x32_bf16(
                        a[m], bf[nh], acc[m][nh], 0, 0, 0);
        }
    }

    // C/D: col(pixel) = ln, row(co within m-tile) = quad*4+reg
    int y = y0 + w;
    #pragma unroll
    for (int nh = 0; nh < 2; ++nh) {
        int x = x0 + nh * 16 + ln;
        if (omode == 2) {
            float* o = (float*)out;
            #pragma unroll
            for (int m = 0; m < 4; ++m)
                #pragma unroll
                for (int reg = 0; reg < 4; ++reg) {
                    int co = m * 16 + quad * 4 + reg;
                    o[((size_t)(b * 64 + co)) * PLANE + (size_t)y * 96 + x] = acc[m][nh][reg];
                }
        } else if (omode == 1) {
            unsigned short* o = (unsigned short*)out;
            #pragma unroll
            for (int m = 0; m < 4; ++m) {
                unsigned short tmp[4] __attribute__((aligned(8)));
                #pragma unroll
                for (int reg = 0; reg < 4; ++reg) tmp[reg] = f2bf(acc[m][nh][reg]);
                *(uint2*)&o[((size_t)b * PLANE + (size_t)y * 96 + x) * 64 + m * 16 + quad * 4]
                    = *(const uint2*)tmp;
            }
        } else {   // omode 3: class-major [b][k9][co][1024]
            unsigned short* o = (unsigned short*)out;
            int k9 = (y % 3) * 3 + (x % 3);
            int l = (y / 3) * 32 + (x / 3);
            #pragma unroll
            for (int m = 0; m < 4; ++m)
                #pragma unroll
                for (int reg = 0; reg < 4; ++reg) {
                    int co = m * 16 + quad * 4 + reg;
                    o[((size_t)(b * 9 + k9) * 64 + co) * 1024 + l] = f2bf(acc[m][nh][reg]);
                }
        }
    }
}

// ---------- scores: per (b,tap) 64x64x1024 MFMA GEMM on class-major data ----
__global__ __launch_bounds__(256) void scores_mfma(
    const unsigned short* __restrict__ kfc, const unsigned short* __restrict__ qfc,
    float* __restrict__ scp, int nseg)
{
    int blk = blockIdx.x;
    int seg = blk % nseg;
    int bk  = blk / nseg;                    // b*9+k
    int lane = threadIdx.x & 63, w = threadIdx.x >> 6;
    int ln = lane & 15, quad = lane >> 4;
    const unsigned short* ka = kfc + (size_t)bk * 64 * 1024;
    const unsigned short* qa = qfc + (size_t)bk * 64 * 1024;

    int Kblk = 1024 / nseg;
    int Kw   = Kblk / 4;
    int nch  = Kw / 32;

    floatx4 acc[4][4];
    #pragma unroll
    for (int i = 0; i < 4; ++i)
        #pragma unroll
        for (int j = 0; j < 4; ++j) acc[i][j] = (floatx4){0.f, 0.f, 0.f, 0.f};

    for (int chk = 0; chk < nch; ++chk) {
        int l = seg * Kblk + w * Kw + chk * 32 + quad * 8;
        short8v a[4], bq[4];
        #pragma unroll
        for (int mi = 0; mi < 4; ++mi)
            a[mi] = *(const short8v*)&ka[(size_t)(mi * 16 + ln) * 1024 + l];
        #pragma unroll
        for (int ni = 0; ni < 4; ++ni)
            bq[ni] = *(const short8v*)&qa[(size_t)(ni * 16 + ln) * 1024 + l];
        #pragma unroll
        for (int mi = 0; mi < 4; ++mi)
            #pragma unroll
            for (int ni = 0; ni < 4; ++ni)
                acc[mi][ni] = __builtin_amdgcn_mfma_f32_16x16x32_bf16(
                    a[mi], bq[ni], acc[mi][ni], 0, 0, 0);
    }

    __shared__ float ls[4][64][65];
    #pragma unroll
    for (int mi = 0; mi < 4; ++mi)
        #pragma unroll
        for (int ni = 0; ni < 4; ++ni)
            #pragma unroll
            for (int reg = 0; reg < 4; ++reg)
                ls[w][ni * 16 + ln][mi * 16 + quad * 4 + reg] = acc[mi][ni][reg];
    __syncthreads();

    float* op = scp + (size_t)seg * SCP_STRIDE + (size_t)bk * 4096;
    int t = threadIdx.x;
    #pragma unroll
    for (int j = 0; j < 16; ++j) {
        int e = t * 16 + j;
        int d = e >> 6, c = e & 63;
        op[e] = ls[0][d][c] + ls[1][d][c] + ls[2][d][c] + ls[3][d][c];
    }
}

// ---------- softmax over (c,k) per (b,d) -> dynamic weights bf16 ------------
__global__ __launch_bounds__(256) void softmax_kernel(
    const float* __restrict__ scp, unsigned short* __restrict__ dynw, int nseg)
{
    int w = threadIdx.x >> 6, c = threadIdx.x & 63;
    int row = blockIdx.x * 4 + w;          // b*64+d
    int b = row >> 6, d = row & 63;
    float v[9];
    float mx = -3.0e38f;
    #pragma unroll
    for (int k = 0; k < 9; ++k) {
        size_t idx = (size_t)(b * 9 + k) * 4096 + d * 64 + c;
        float s = scp[idx];
        for (int g = 1; g < nseg; ++g) s += scp[(size_t)g * SCP_STRIDE + idx];
        v[k] = s * (1.0f / 24.0f);         // 1/sqrt(576)
        mx = fmaxf(mx, v[k]);
    }
    #pragma unroll
    for (int o = 32; o; o >>= 1) mx = fmaxf(mx, __shfl_xor(mx, o));
    float sum = 0.f;
    #pragma unroll
    for (int k = 0; k < 9; ++k) { v[k] = __expf(v[k] - mx); sum += v[k]; }
    #pragma unroll
    for (int o = 32; o; o >>= 1) sum += __shfl_xor(sum, o);
    float inv = 1.0f / sum;
    #pragma unroll
    for (int k = 0; k < 9; ++k)
        dynw[((size_t)(b * 9 + k) * 64 + d) * 64 + c] = f2bf(v[k] * inv);
}

extern "C" void kernel_launch(void* const* d_in, const int* in_sizes, int n_in,
                              void* d_out, int out_size, void* d_ws, size_t ws_size,
                              hipStream_t stream) {
    (void)in_sizes; (void)n_in; (void)out_size;
    const float* x1 = (const float*)d_in[0];
    const float* x2 = (const float*)d_in[1];
    const float* w1 = (const float*)d_in[2];
    const float* w2 = (const float*)d_in[3];
    const float* w3 = (const float*)d_in[4];
    float* out = (float*)d_out;

    char* ws = (char*)d_ws;
    constexpr size_t XHB = (size_t)16 * PLANE * 64 * 2;   // 18,874,368 B
    constexpr size_t WLB = 221184;                        // 3*9*4096*2
    constexpr size_t DWB = 1179648;                       // 16*9*4096*2
    constexpr size_t SCB = (size_t)SCP_STRIDE * 4;        // 2,359,296 B per seg

    unsigned short* xh1  = (unsigned short*)(ws);
    unsigned short* xh2  = (unsigned short*)(ws + XHB);
    unsigned short* kfc  = (unsigned short*)(ws + 2 * XHB);
    unsigned short* qfc  = (unsigned short*)(ws + 3 * XHB);
    unsigned short* wl   = (unsigned short*)(ws + 4 * XHB);
    unsigned short* dynw = (unsigned short*)(ws + 4 * XHB + WLB);
    float* scp = (float*)(ws + 4 * XHB + WLB + DWB);
    size_t base = 4 * XHB + WLB + DWB;

    int nseg; bool fused3;
    if (ws_size >= base + 2 * SCB + XHB)      { nseg = 2; fused3 = true; }
    else if (ws_size >= base + 1 * SCB + XHB) { nseg = 1; fused3 = true; }
    else { nseg = (ws_size >= base + 2 * SCB) ? 2 : 1; fused3 = false; }
    unsigned short* vf = (unsigned short*)(ws + base + (size_t)nseg * SCB);

    nchw2nhwc_bf16<<<dim3(3072), dim3(256), 0, stream>>>(x1, xh1, x2, xh2);
    wreorder<<<dim3(27), dim3(256), 0, stream>>>(w1, w2, w3, wl);

    if (fused3) {
        // kf, qf, vf in one dispatch (3456 blocks)
        conv_mfma<<<dim3(3456), dim3(256), 0, stream>>>(
            xh1, xh2, xh1, wl, kfc, qfc, vf, 3, 3, 1, 0);
        scores_mfma<<<dim3(144 * nseg), dim3(256), 0, stream>>>(kfc, qfc, scp, nseg);
        softmax_kernel<<<dim3(256), dim3(256), 0, stream>>>(scp, dynw, nseg);
        conv_mfma<<<dim3(1152), dim3(256), 0, stream>>>(
            vf, nullptr, nullptr, dynw, out, nullptr, nullptr, 2, 0, 0, 1);
    } else {
        // kf, qf fused; vf written into xh2 after scores consumed qfc inputs
        conv_mfma<<<dim3(2304), dim3(256), 0, stream>>>(
            xh1, xh2, nullptr, wl, kfc, qfc, nullptr, 3, 3, 0, 0);
        scores_mfma<<<dim3(144 * nseg), dim3(256), 0, stream>>>(kfc, qfc, scp, nseg);
        softmax_kernel<<<dim3(256), dim3(256), 0, stream>>>(scp, dynw, nseg);
        conv_mfma<<<dim3(1152), dim3(256), 0, stream>>>(
            xh1, nullptr, nullptr, wl + 18 * 4096, xh2, nullptr, nullptr, 1, 0, 0, 0);
        conv_mfma<<<dim3(1152), dim3(256), 0, stream>>>(
            xh2, nullptr, nullptr, dynw, out, nullptr, nullptr, 2, 0, 0, 1);
    }
}

// Round 5
// 244.820 us; speedup vs baseline: 1.4319x; 1.4319x over previous
//
#include <hip/hip_runtime.h>

// B=16, C=64->64, H=W=96, 3x3 pad-1 convs + 9-tap dynamic conv from attention.
// Convs: bf16 MFMA implicit GEMM, 6x48-px tiles (3-aligned so each of the 9
// pixel classes has exactly 32 px/tile). kf/qf write a class-major layout
// [b][k9][co][1024] with a tile-permuted (but kfc/qfc-consistent) l-order so
// epilogue stores are coalesced 32B runs. Scores: bf16 MFMA batched GEMM.

typedef __attribute__((ext_vector_type(8))) short short8v;   // 8 bf16 = 4 VGPRs
typedef __attribute__((ext_vector_type(4))) float floatx4;
typedef __attribute__((ext_vector_type(4))) unsigned int uint4v;

constexpr int PLANE = 9216;              // 96*96
constexpr int SCP_STRIDE = 589824;       // 16*9*4096 floats per K-segment

__device__ __forceinline__ unsigned short f2bf(float f) {
    unsigned int u = __float_as_uint(f);
    u = (u + 0x7FFFu + ((u >> 16) & 1u)) >> 16;
    return (unsigned short)u;
}

// ---------- fp32 NCHW -> bf16 NHWC, both inputs in one dispatch -------------
__global__ __launch_bounds__(256) void nchw2nhwc_bf16(
    const float* __restrict__ x1, unsigned short* __restrict__ xh1,
    const float* __restrict__ x2, unsigned short* __restrict__ xh2)
{
    int blk = blockIdx.x;
    const float* x = (blk < 1536) ? x1 : x2;
    unsigned short* xh = (blk < 1536) ? xh1 : xh2;
    if (blk >= 1536) blk -= 1536;
    int b = blk / 96, y = blk - b * 96;
    __shared__ float ls[64][96];
    const float* xp = x + (size_t)b * 64 * PLANE + (size_t)y * 96;
    for (int i = threadIdx.x; i < 64 * 96; i += 256) {
        int ci = i / 96, xc = i - ci * 96;
        ls[ci][xc] = xp[(size_t)ci * PLANE + xc];
    }
    __syncthreads();
    unsigned short* op = xh + ((size_t)b * PLANE + (size_t)y * 96) * 64;
    for (int i = threadIdx.x; i < 96 * 8; i += 256) {
        int xc = i >> 3, cg = i & 7;
        unsigned short tmp[8] __attribute__((aligned(16)));
        #pragma unroll
        for (int j = 0; j < 8; ++j) tmp[j] = f2bf(ls[cg * 8 + j][xc]);
        *(uint4v*)&op[(size_t)xc * 64 + cg * 8] = *(const uint4v*)tmp;
    }
}

// ---------- weights [co][ci][kh][kw] fp32 -> [tap][co][ci] bf16 -------------
__global__ __launch_bounds__(256) void wreorder(
    const float* __restrict__ w1, const float* __restrict__ w2,
    const float* __restrict__ w3, unsigned short* __restrict__ wl)
{
    int blk = blockIdx.x;
    int wi = blk / 9, k9 = blk - wi * 9;
    const float* w = (wi == 0) ? w1 : ((wi == 1) ? w2 : w3);
    unsigned short* o = wl + (size_t)wi * 9 * 4096 + (size_t)k9 * 4096;
    for (int i = threadIdx.x; i < 4096; i += 256)   // i = co*64+ci
        o[i] = f2bf(w[(size_t)i * 9 + k9]);
}

// ---------- MFMA conv v5: 64 co x 288 px (6 rows x 48 cols) per block -------
// 3 waves of 64; each wave: all 64 co (4 m-tiles) x 96 px (6 n-tiles).
// worg = (omode==3): n-tiles are (class kc, y3) pairs, lanes are x3 -> class-
// major epilogue is lane-contiguous. Otherwise n-tiles are (row, 16-col grp).
// 2-stage software pipeline: step s+1's 4 A-globals + 6 ds_reads issued before
// step s's 24 MFMAs. omode: 1 = bf16 NHWC, 2 = fp32 NCHW, 3 = class-major.
__global__ __launch_bounds__(192, 2) void conv_mfma(
    const unsigned short* __restrict__ in0,
    const unsigned short* __restrict__ in1,
    const unsigned short* __restrict__ in2,
    const unsigned short* __restrict__ wl,
    void* __restrict__ o0, void* __restrict__ o1, void* __restrict__ o2,
    int om0, int om1, int om2, int dynb)
{
    int blk = blockIdx.x;
    int cid = blk >> 9;                  // 512 blocks per conv
    int r0  = blk & 511;
    int xt = r0 & 1, yt = (r0 >> 1) & 15, b = r0 >> 5;
    int x0 = xt * 48, y0 = yt * 6;

    const unsigned short* xin = (cid == 0) ? in0 : (cid == 1) ? in1 : in2;
    void* out  = (cid == 0) ? o0 : (cid == 1) ? o1 : o2;
    int omode  = (cid == 0) ? om0 : (cid == 1) ? om1 : om2;

    // halo 8 rows x 50 cols x 64 ci, XOR-swizzled: group g at slot g^(pc&7)
    __shared__ __align__(16) unsigned short xs[8 * 50 * 64];   // 51,200 B

    const unsigned short* xb = xin + (size_t)b * PLANE * 64;
    for (int i = threadIdx.x; i < 3200; i += 192) {
        int g = i & 7, pix = i >> 3;
        int pr = pix / 50, pc = pix - pr * 50;
        int y = y0 - 1 + pr, x = x0 - 1 + pc;
        uint4v v = {0u, 0u, 0u, 0u};
        if ((unsigned)y < 96u && (unsigned)x < 96u)
            v = *(const uint4v*)&xb[((size_t)y * 96 + x) * 64 + g * 8];
        *(uint4v*)&xs[pix * 64 + (g ^ (pc & 7)) * 8] = v;
    }
    __syncthreads();

    int lane = threadIdx.x & 63;
    int w = threadIdx.x >> 6;            // wave 0..2
    int ln = lane & 15, q = lane >> 4;

    const unsigned short* wb = wl + (dynb ? (size_t)b * 9 * 4096
                                          : (size_t)cid * 9 * 4096);
    int worg = (omode == 3);

    // pixel geometry per n-tile (yloc wave-uniform, xloc lane-varying)
    int yloc[6], xloc[6];
    #pragma unroll
    for (int nt = 0; nt < 6; ++nt) {
        if (worg) {          // class tiles: kc = nt>>1, y3 = nt&1; k9 = w*3+kc
            yloc[nt] = (nt & 1) * 3 + w;
            xloc[nt] = 3 * ln + (nt >> 1);
        } else {             // contiguous: rsel = nt/3, cg = nt%3
            yloc[nt] = w * 2 + (nt / 3);
            xloc[nt] = (nt % 3) * 16 + ln;
        }
    }

    floatx4 acc[4][6];
    #pragma unroll
    for (int m = 0; m < 4; ++m)
        #pragma unroll
        for (int nt = 0; nt < 6; ++nt) acc[m][nt] = (floatx4){0.f, 0.f, 0.f, 0.f};

    short8v A[2][4], Bf[2][6];

    // step s: tap = s>>1 (ty=tap/3, tx=tap%3), ci-half ch = s&1
    #define LOAD_STEP(s, buf)                                                   \
    {                                                                           \
        int tap = (s) >> 1, ch = (s) & 1;                                       \
        int ty = tap / 3, tx = tap - ty * 3;                                    \
        _Pragma("unroll")                                                       \
        for (int m = 0; m < 4; ++m)                                             \
            A[buf][m] = *(const short8v*)                                       \
                &wb[((size_t)tap * 64 + m * 16 + ln) * 64 + ch * 32 + q * 8];   \
        _Pragma("unroll")                                                       \
        for (int nt = 0; nt < 6; ++nt) {                                        \
            int hx = xloc[nt] + tx;                                             \
            Bf[buf][nt] = *(const short8v*)                                     \
                &xs[((yloc[nt] + ty) * 50 + hx) * 64 + (((ch << 2) + q) ^ (hx & 7)) * 8]; \
        }                                                                       \
    }

    LOAD_STEP(0, 0)
    #pragma unroll
    for (int s = 0; s < 18; ++s) {
        int cur = s & 1;
        if (s < 17) LOAD_STEP(s + 1, cur ^ 1)
        #pragma unroll
        for (int m = 0; m < 4; ++m)
            #pragma unroll
            for (int nt = 0; nt < 6; ++nt)
                acc[m][nt] = __builtin_amdgcn_mfma_f32_16x16x32_bf16(
                    A[cur][m], Bf[cur][nt], acc[m][nt], 0, 0, 0);
    }
    #undef LOAD_STEP

    // C/D: col = ln (pixel), row(co within m-tile) = q*4+reg
    if (omode == 3) {
        // [b][k9][co][1024], l = (yt*2+xt)*32 + y3*16 + x3(=ln)
        unsigned short* o = (unsigned short*)out;
        int l0 = (yt * 2 + xt) * 32;
        #pragma unroll
        for (int nt = 0; nt < 6; ++nt) {
            int k9 = w * 3 + (nt >> 1);
            int l = l0 + (nt & 1) * 16 + ln;
            #pragma unroll
            for (int m = 0; m < 4; ++m)
                #pragma unroll
                for (int reg = 0; reg < 4; ++reg) {
                    int co = m * 16 + q * 4 + reg;
                    o[((size_t)(b * 9 + k9) * 64 + co) * 1024 + l] = f2bf(acc[m][nt][reg]);
                }
        }
    } else if (omode == 2) {
        float* o = (float*)out;
        #pragma unroll
        for (int nt = 0; nt < 6; ++nt) {
            int y = y0 + yloc[nt], x = x0 + xloc[nt];
            #pragma unroll
            for (int m = 0; m < 4; ++m)
                #pragma unroll
                for (int reg = 0; reg < 4; ++reg) {
                    int co = m * 16 + q * 4 + reg;
                    o[((size_t)(b * 64 + co)) * PLANE + (size_t)y * 96 + x] = acc[m][nt][reg];
                }
        }
    } else {   // omode 1: bf16 NHWC
        unsigned short* o = (unsigned short*)out;
        #pragma unroll
        for (int nt = 0; nt < 6; ++nt) {
            int y = y0 + yloc[nt], x = x0 + xloc[nt];
            #pragma unroll
            for (int m = 0; m < 4; ++m) {
                unsigned short tmp[4] __attribute__((aligned(8)));
                #pragma unroll
                for (int reg = 0; reg < 4; ++reg) tmp[reg] = f2bf(acc[m][nt][reg]);
                *(uint2*)&o[((size_t)b * PLANE + (size_t)y * 96 + x) * 64 + m * 16 + q * 4]
                    = *(const uint2*)tmp;
            }
        }
    }
}

// ---------- scores: per (b,tap) 64x64x1024 MFMA GEMM on class-major data ----
__global__ __launch_bounds__(256) void scores_mfma(
    const unsigned short* __restrict__ kfc, const unsigned short* __restrict__ qfc,
    float* __restrict__ scp, int nseg)
{
    int blk = blockIdx.x;
    int seg = blk % nseg;
    int bk  = blk / nseg;                    // b*9+k
    int lane = threadIdx.x & 63, w = threadIdx.x >> 6;
    int ln = lane & 15, quad = lane >> 4;
    const unsigned short* ka = kfc + (size_t)bk * 64 * 1024;
    const unsigned short* qa = qfc + (size_t)bk * 64 * 1024;

    int Kblk = 1024 / nseg;
    int Kw   = Kblk / 4;
    int nch  = Kw / 32;

    floatx4 acc[4][4];
    #pragma unroll
    for (int i = 0; i < 4; ++i)
        #pragma unroll
        for (int j = 0; j < 4; ++j) acc[i][j] = (floatx4){0.f, 0.f, 0.f, 0.f};

    for (int chk = 0; chk < nch; ++chk) {
        int l = seg * Kblk + w * Kw + chk * 32 + quad * 8;
        short8v a[4], bq[4];
        #pragma unroll
        for (int mi = 0; mi < 4; ++mi)
            a[mi] = *(const short8v*)&ka[(size_t)(mi * 16 + ln) * 1024 + l];
        #pragma unroll
        for (int ni = 0; ni < 4; ++ni)
            bq[ni] = *(const short8v*)&qa[(size_t)(ni * 16 + ln) * 1024 + l];
        #pragma unroll
        for (int mi = 0; mi < 4; ++mi)
            #pragma unroll
            for (int ni = 0; ni < 4; ++ni)
                acc[mi][ni] = __builtin_amdgcn_mfma_f32_16x16x32_bf16(
                    a[mi], bq[ni], acc[mi][ni], 0, 0, 0);
    }

    __shared__ float ls[4][64][65];
    #pragma unroll
    for (int mi = 0; mi < 4; ++mi)
        #pragma unroll
        for (int ni = 0; ni < 4; ++ni)
            #pragma unroll
            for (int reg = 0; reg < 4; ++reg)
                ls[w][ni * 16 + ln][mi * 16 + quad * 4 + reg] = acc[mi][ni][reg];
    __syncthreads();

    float* op = scp + (size_t)seg * SCP_STRIDE + (size_t)bk * 4096;
    int t = threadIdx.x;
    #pragma unroll
    for (int j = 0; j < 16; ++j) {
        int e = t * 16 + j;
        int d = e >> 6, c = e & 63;
        op[e] = ls[0][d][c] + ls[1][d][c] + ls[2][d][c] + ls[3][d][c];
    }
}

// ---------- softmax over (c,k) per (b,d) -> dynamic weights bf16 ------------
__global__ __launch_bounds__(256) void softmax_kernel(
    const float* __restrict__ scp, unsigned short* __restrict__ dynw, int nseg)
{
    int w = threadIdx.x >> 6, c = threadIdx.x & 63;
    int row = blockIdx.x * 4 + w;          // b*64+d
    int b = row >> 6, d = row & 63;
    float v[9];
    float mx = -3.0e38f;
    #pragma unroll
    for (int k = 0; k < 9; ++k) {
        size_t idx = (size_t)(b * 9 + k) * 4096 + d * 64 + c;
        float s = scp[idx];
        for (int g = 1; g < nseg; ++g) s += scp[(size_t)g * SCP_STRIDE + idx];
        v[k] = s * (1.0f / 24.0f);         // 1/sqrt(576)
        mx = fmaxf(mx, v[k]);
    }
    #pragma unroll
    for (int o = 32; o; o >>= 1) mx = fmaxf(mx, __shfl_xor(mx, o));
    float sum = 0.f;
    #pragma unroll
    for (int k = 0; k < 9; ++k) { v[k] = __expf(v[k] - mx); sum += v[k]; }
    #pragma unroll
    for (int o = 32; o; o >>= 1) sum += __shfl_xor(sum, o);
    float inv = 1.0f / sum;
    #pragma unroll
    for (int k = 0; k < 9; ++k)
        dynw[((size_t)(b * 9 + k) * 64 + d) * 64 + c] = f2bf(v[k] * inv);
}

extern "C" void kernel_launch(void* const* d_in, const int* in_sizes, int n_in,
                              void* d_out, int out_size, void* d_ws, size_t ws_size,
                              hipStream_t stream) {
    (void)in_sizes; (void)n_in; (void)out_size;
    const float* x1 = (const float*)d_in[0];
    const float* x2 = (const float*)d_in[1];
    const float* w1 = (const float*)d_in[2];
    const float* w2 = (const float*)d_in[3];
    const float* w3 = (const float*)d_in[4];
    float* out = (float*)d_out;

    char* ws = (char*)d_ws;
    constexpr size_t XHB = (size_t)16 * PLANE * 64 * 2;   // 18,874,368 B
    constexpr size_t WLB = 221184;                        // 3*9*4096*2
    constexpr size_t DWB = 1179648;                       // 16*9*4096*2
    constexpr size_t SCB = (size_t)SCP_STRIDE * 4;        // 2,359,296 B per seg

    unsigned short* xh1  = (unsigned short*)(ws);
    unsigned short* xh2  = (unsigned short*)(ws + XHB);
    unsigned short* kfc  = (unsigned short*)(ws + 2 * XHB);
    unsigned short* qfc  = (unsigned short*)(ws + 3 * XHB);
    unsigned short* wl   = (unsigned short*)(ws + 4 * XHB);
    unsigned short* dynw = (unsigned short*)(ws + 4 * XHB + WLB);
    float* scp = (float*)(ws + 4 * XHB + WLB + DWB);
    size_t base = 4 * XHB + WLB + DWB;

    int nseg; bool fused3;
    if (ws_size >= base + 2 * SCB + XHB)      { nseg = 2; fused3 = true; }
    else if (ws_size >= base + 1 * SCB + XHB) { nseg = 1; fused3 = true; }
    else { nseg = (ws_size >= base + 2 * SCB) ? 2 : 1; fused3 = false; }
    unsigned short* vf = (unsigned short*)(ws + base + (size_t)nseg * SCB);

    nchw2nhwc_bf16<<<dim3(3072), dim3(256), 0, stream>>>(x1, xh1, x2, xh2);
    wreorder<<<dim3(27), dim3(256), 0, stream>>>(w1, w2, w3, wl);

    if (fused3) {
        // kf (class-major), qf (class-major), vf (NHWC) in one dispatch
        conv_mfma<<<dim3(1536), dim3(192), 0, stream>>>(
            xh1, xh2, xh1, wl, kfc, qfc, vf, 3, 3, 1, 0);
        scores_mfma<<<dim3(144 * nseg), dim3(256), 0, stream>>>(kfc, qfc, scp, nseg);
        softmax_kernel<<<dim3(256), dim3(256), 0, stream>>>(scp, dynw, nseg);
        conv_mfma<<<dim3(512), dim3(192), 0, stream>>>(
            vf, nullptr, nullptr, dynw, out, nullptr, nullptr, 2, 0, 0, 1);
    } else {
        conv_mfma<<<dim3(1024), dim3(192), 0, stream>>>(
            xh1, xh2, nullptr, wl, kfc, qfc, nullptr, 3, 3, 0, 0);
        scores_mfma<<<dim3(144 * nseg), dim3(256), 0, stream>>>(kfc, qfc, scp, nseg);
        softmax_kernel<<<dim3(256), dim3(256), 0, stream>>>(scp, dynw, nseg);
        conv_mfma<<<dim3(512), dim3(192), 0, stream>>>(
            xh1, nullptr, nullptr, wl + 18 * 4096, xh2, nullptr, nullptr, 1, 0, 0, 0);
        conv_mfma<<<dim3(512), dim3(192), 0, stream>>>(
            xh2, nullptr, nullptr, dynw, out, nullptr, nullptr, 2, 0, 0, 1);
    }
}